// Round 5
// baseline (691.678 us; speedup 1.0000x reference)
//
#include <hip/hip_runtime.h>
#include <stdint.h>
#include <stddef.h>

typedef __bf16 bf16;
typedef __attribute__((ext_vector_type(8))) __bf16 bf16x8;
typedef __attribute__((ext_vector_type(4))) __bf16 bf16x4;
typedef __attribute__((ext_vector_type(4))) float f32x4;

#define NN 4096
#define HIDD 512
#define NE 65536

// ---------- async global->LDS, 16B per lane, wave-uniform LDS base ----------
__device__ inline void gll16(const void* g, void* l) {
    __builtin_amdgcn_global_load_lds(
        (const __attribute__((address_space(1))) void*)g,
        (__attribute__((address_space(3))) void*)l, 16, 0, 0);
}

// ---------- fp32 -> bf16 elementwise convert (n multiple of 1024) ----------
__global__ void cvt_f32_bf16(const float* __restrict__ in, bf16* __restrict__ out, int n) {
    int i = (blockIdx.x * 256 + threadIdx.x) * 4;
    if (i >= n) return;
    float4 v = *reinterpret_cast<const float4*>(in + i);
    bf16x4 o;
    o[0] = (bf16)v.x; o[1] = (bf16)v.y; o[2] = (bf16)v.z; o[3] = (bf16)v.w;
    *reinterpret_cast<bf16x4*>(out + i) = o;
}

// ---------- sum S bf16 slices of n elems -> bf16 (n multiple of 2048) ----------
__global__ void reduce_bf16_slices(const bf16* __restrict__ in, bf16* __restrict__ out,
                                   int n, int S) {
    int i = (blockIdx.x * 256 + threadIdx.x) * 8;
    if (i >= n) return;
    float acc[8] = {};
    for (int k = 0; k < S; ++k) {
        bf16x8 v = *reinterpret_cast<const bf16x8*>(in + (size_t)k * n + i);
#pragma unroll
        for (int j = 0; j < 8; ++j) acc[j] += (float)v[j];
    }
    bf16x8 o;
#pragma unroll
    for (int j = 0; j < 8; ++j) o[j] = (bf16)acc[j];
    *reinterpret_cast<bf16x8*>(out + i) = o;
}

// ---------- sum S bf16 slices [NN,HIDD]; out = (sum * rs[row]) + bias[col], bf16 ----------
template<bool RS>
__global__ void reduce_affine512(const bf16* __restrict__ in, bf16* __restrict__ out,
                                 int S, const float* __restrict__ rs,
                                 const float* __restrict__ bias) {
    int i = (blockIdx.x * 256 + threadIdx.x) * 8;   // over NN*HIDD
    const int n = NN * HIDD;
    float acc[8] = {};
    for (int k = 0; k < S; ++k) {
        bf16x8 v = *reinterpret_cast<const bf16x8*>(in + (size_t)k * n + i);
#pragma unroll
        for (int j = 0; j < 8; ++j) acc[j] += (float)v[j];
    }
    int col = i & (HIDD - 1);
    int row = i >> 9;
    float scale = RS ? rs[row] : 1.f;
    float4 bA = *reinterpret_cast<const float4*>(bias + col);
    float4 bB = *reinterpret_cast<const float4*>(bias + col + 4);
    float bb[8] = {bA.x, bA.y, bA.z, bA.w, bB.x, bB.y, bB.z, bB.w};
    bf16x8 o;
#pragma unroll
    for (int j = 0; j < 8; ++j) o[j] = (bf16)(acc[j] * scale + bb[j]);
    *reinterpret_cast<bf16x8*>(out + i) = o;
}

// ---------- fp32 transpose -> bf16 with column zero-padding (small, knn) ----------
__global__ void transpose_pad_f32(const float* __restrict__ in, bf16* __restrict__ out,
                                  int R, int C, int Cpad) {
    __shared__ bf16 tile[32][33];
    int c0 = blockIdx.x * 32, r0 = blockIdx.y * 32;
    int tx = threadIdx.x, ty = threadIdx.y;
    for (int i = ty; i < 32; i += 8) {
        int r = r0 + i, c = c0 + tx;
        bf16 v = (bf16)0.f;
        if (r < R && c < C) v = (bf16)in[(size_t)r * C + c];
        tile[i][tx] = v;
    }
    __syncthreads();
    for (int i = ty; i < 32; i += 8) {
        int oc = c0 + i, orow = r0 + tx;
        if (oc < Cpad && orow < R) out[(size_t)oc * R + orow] = tile[tx][i];
    }
}

// ---------- vectorized fp32 transpose -> bf16, dims multiple of 64 ----------
__global__ __launch_bounds__(256)
void transpose64_f32_bf16(const float* __restrict__ in, bf16* __restrict__ out,
                          int R, int C) {
    __shared__ bf16 tile[64][66];
    int c0 = blockIdx.x * 64, r0 = blockIdx.y * 64;
    int tx = threadIdx.x & 15, ty = threadIdx.x >> 4;
#pragma unroll
    for (int rr = 0; rr < 4; ++rr) {
        int r = ty + rr * 16;
        float4 v = *reinterpret_cast<const float4*>(in + (size_t)(r0 + r) * C + c0 + tx * 4);
        tile[r][tx * 4 + 0] = (bf16)v.x;
        tile[r][tx * 4 + 1] = (bf16)v.y;
        tile[r][tx * 4 + 2] = (bf16)v.z;
        tile[r][tx * 4 + 3] = (bf16)v.w;
    }
    __syncthreads();
#pragma unroll
    for (int cc = 0; cc < 4; ++cc) {
        int c = ty + cc * 16;
        bf16x4 o;
#pragma unroll
        for (int j = 0; j < 4; ++j) o[j] = tile[tx * 4 + j][c];
        *reinterpret_cast<bf16x4*>(out + (size_t)(c0 + c) * R + r0 + tx * 4) = o;
    }
}

// ---------- bf16 transpose: out[c][r] = in[r][c], dims multiple of 32 ----------
__global__ void transpose_bf16(const bf16* __restrict__ in, bf16* __restrict__ out,
                               int R, int C) {
    __shared__ bf16 tile[32][33];
    int c0 = blockIdx.x * 32, r0 = blockIdx.y * 32;
    int tx = threadIdx.x, ty = threadIdx.y;
    for (int i = ty; i < 32; i += 8)
        tile[i][tx] = in[(size_t)(r0 + i) * C + c0 + tx];
    __syncthreads();
    for (int i = ty; i < 32; i += 8)
        out[(size_t)(c0 + i) * R + r0 + tx] = tile[tx][i];
}

// ---------- NT GEMM: C[M,N] = A[M,K] * B[N,K]^T, m97 structure ----------
// OMODE: 0 = fp32 out at Cp + z*M*N; 1 = bf16 out; 2 = bf16 partial at Cp + z*M*N
// BF32: B operand is fp32 in global; converted to bf16 during LDS staging.
template<int OMODE, bool BF32>
__global__ __launch_bounds__(256)
void gemm_nt(const bf16* __restrict__ A, const void* __restrict__ Bv,
             void* __restrict__ Cp, int M, int N, int K) {
    __shared__ __align__(16) bf16 As[128 * 32];
    __shared__ __align__(16) bf16 Bs[128 * 32];
    const int tid  = threadIdx.x;
    const int wave = tid >> 6;
    const int lane = tid & 63;
    const int m0 = blockIdx.y * 128, n0 = blockIdx.x * 128;
    const int lrow = lane >> 2;
    const int lcol = (lane & 3) * 8;
    const int c0 = wave * 2;
    const size_t arow0 = (size_t)(m0 + c0 * 16 + lrow) * K + lcol;
    const size_t arow1 = (size_t)(m0 + (c0 + 1) * 16 + lrow) * K + lcol;
    const size_t brow0 = (size_t)(n0 + c0 * 16 + lrow) * K + lcol;
    const size_t brow1 = (size_t)(n0 + (c0 + 1) * 16 + lrow) * K + lcol;
    bf16* asd0 = &As[c0 * 512];
    bf16* asd1 = &As[(c0 + 1) * 512];
    bf16* bsd0 = &Bs[c0 * 512];
    bf16* bsd1 = &Bs[(c0 + 1) * 512];
    const bf16*  Bb = (const bf16*)Bv;
    const float* Bf = (const float*)Bv;
    // BF32 staging: 2 threads per B-row, 16 k-elems each
    const int trow  = tid >> 1;
    const int khalf = (tid & 1) * 16;
    const size_t bfrow = (size_t)(n0 + trow) * K + khalf;

    f32x4 acc[4][4] = {};

    const int wm = (wave >> 1) * 64;
    const int wn = (wave & 1) * 64;
    const int fm = wm + (lane & 15);
    const int fn = wn + (lane & 15);
    const int fk = (lane >> 4) * 8;

    const int kper = K / gridDim.z;
    const int kz0 = blockIdx.z * kper;
    const int kz1 = kz0 + kper;

    for (int k0 = kz0; k0 < kz1; k0 += 32) {
        gll16(A + arow0 + k0, asd0);
        gll16(A + arow1 + k0, asd1);
        if (BF32) {
            const float* src = Bf + bfrow + k0;
            float4 v0 = *reinterpret_cast<const float4*>(src + 0);
            float4 v1 = *reinterpret_cast<const float4*>(src + 4);
            float4 v2 = *reinterpret_cast<const float4*>(src + 8);
            float4 v3 = *reinterpret_cast<const float4*>(src + 12);
            bf16x8 p0, p1;
            p0[0] = (bf16)v0.x; p0[1] = (bf16)v0.y; p0[2] = (bf16)v0.z; p0[3] = (bf16)v0.w;
            p0[4] = (bf16)v1.x; p0[5] = (bf16)v1.y; p0[6] = (bf16)v1.z; p0[7] = (bf16)v1.w;
            p1[0] = (bf16)v2.x; p1[1] = (bf16)v2.y; p1[2] = (bf16)v2.z; p1[3] = (bf16)v2.w;
            p1[4] = (bf16)v3.x; p1[5] = (bf16)v3.y; p1[6] = (bf16)v3.z; p1[7] = (bf16)v3.w;
            *reinterpret_cast<bf16x8*>(&Bs[trow * 32 + khalf]) = p0;
            *reinterpret_cast<bf16x8*>(&Bs[trow * 32 + khalf + 8]) = p1;
        } else {
            gll16(Bb + brow0 + k0, bsd0);
            gll16(Bb + brow1 + k0, bsd1);
        }
        __syncthreads();
        bf16x8 af[4], bg[4];
#pragma unroll
        for (int i = 0; i < 4; ++i)
            af[i] = *reinterpret_cast<const bf16x8*>(&As[(fm + i * 16) * 32 + fk]);
#pragma unroll
        for (int j = 0; j < 4; ++j)
            bg[j] = *reinterpret_cast<const bf16x8*>(&Bs[(fn + j * 16) * 32 + fk]);
#pragma unroll
        for (int i = 0; i < 4; ++i)
#pragma unroll
            for (int j = 0; j < 4; ++j)
                acc[i][j] = __builtin_amdgcn_mfma_f32_16x16x32_bf16(af[i], bg[j], acc[i][j], 0, 0, 0);
        __syncthreads();
    }

    const int rbase = m0 + wm + (lane >> 4) * 4;
    const int cbase = n0 + wn + (lane & 15);
    float* outf = (float*)Cp + (size_t)blockIdx.z * M * N;
    bf16*  outb = (bf16*)Cp;
    bf16*  outp = (bf16*)Cp + (size_t)blockIdx.z * M * N;
#pragma unroll
    for (int i = 0; i < 4; ++i) {
#pragma unroll
        for (int j = 0; j < 4; ++j) {
            int col = cbase + j * 16;
#pragma unroll
            for (int r = 0; r < 4; ++r) {
                int row = rbase + i * 16 + r;
                float v = acc[i][j][r];
                if (OMODE == 0)      outf[(size_t)row * N + col] = v;
                else if (OMODE == 1) outb[(size_t)row * N + col] = (bf16)v;
                else                 outp[(size_t)row * N + col] = (bf16)v;
            }
        }
    }
}

// ---------- colnorm partials over 2 fp32 R-slices ----------
__global__ void colnorm_part2(const bf16* __restrict__ Ht, const float* __restrict__ Rf,
                              float* __restrict__ n2) {
    int i = blockIdx.x * 128 + threadIdx.x;   // 32 x-blocks cover 4096 cols
    int a0 = blockIdx.y * 64;                 // 8 y-blocks cover 512 rows
    const float* R1 = Rf + (size_t)HIDD * NN;
    float s = 0.f;
    for (int a = a0; a < a0 + 64; ++a)
        s += (Rf[(size_t)a * NN + i] + R1[(size_t)a * NN + i]) * (float)Ht[(size_t)a * NN + i];
    atomicAdd(&n2[i], s);
}

__global__ void colnorm_fin(const float* __restrict__ n2, float* __restrict__ inv) {
    int i = blockIdx.x * 256 + threadIdx.x;
    inv[i] = 1.f / fmaxf(sqrtf(n2[i]), 1e-12f);
}

// ---------- CSR build ----------
__global__ void csr_count(const int* __restrict__ ei, int* __restrict__ cnt, int E) {
    int e = blockIdx.x * 256 + threadIdx.x;
    if (e < E) atomicAdd(&cnt[ei[e]], 1);
}

__global__ void scan_4096(const int* __restrict__ cnt, int* __restrict__ rs) {
    __shared__ int s[1024];
    int t = threadIdx.x;
    int b = t * 4;
    int a0 = cnt[b], a1 = cnt[b + 1], a2 = cnt[b + 2], a3 = cnt[b + 3];
    int tot = a0 + a1 + a2 + a3;
    s[t] = tot;
    __syncthreads();
    for (int off = 1; off < 1024; off <<= 1) {
        int v = (t >= off) ? s[t - off] : 0;
        __syncthreads();
        s[t] += v;
        __syncthreads();
    }
    int excl = s[t] - tot;
    rs[b] = excl; rs[b + 1] = excl + a0; rs[b + 2] = excl + a0 + a1; rs[b + 3] = excl + a0 + a1 + a2;
    if (t == 1023) rs[4096] = s[1023];
}

__global__ void csr_scatter(const int* __restrict__ ei, const float* __restrict__ ew,
                            int* __restrict__ cur, int* __restrict__ ccol,
                            float* __restrict__ cw, int E) {
    int e = blockIdx.x * 256 + threadIdx.x;
    if (e < E) {
        int r = ei[e];
        int p = atomicAdd(&cur[r], 1);
        ccol[p] = ei[E + e];
        cw[p] = ew[e];
    }
}

// ---------- one Euler diffusion step in bf16 ----------
__global__ void ode_step_bf16(const bf16* __restrict__ xin, const bf16* __restrict__ x0,
                              bf16* __restrict__ xout, const int* __restrict__ rs,
                              const int* __restrict__ ccol, const float* __restrict__ cw,
                              const float* __restrict__ alpha_p, const float* __restrict__ beta_p) {
    int row = blockIdx.x * 4 + (threadIdx.x >> 6);
    int lane = threadIdx.x & 63;
    float alpha = 1.f / (1.f + expf(-alpha_p[0]));
    float beta = beta_p[0];
    const bf16x8* xin8 = (const bf16x8*)xin;
    float acc[8] = {};
    int p0 = rs[row], p1 = rs[row + 1];
    for (int p = p0; p < p1; ++p) {
        int c = ccol[p]; float w = cw[p];
        bf16x8 v = xin8[(size_t)c * 64 + lane];
#pragma unroll
        for (int j = 0; j < 8; ++j) acc[j] += w * (float)v[j];
    }
    bf16x8 xi = xin8[(size_t)row * 64 + lane];
    bf16x8 xz = ((const bf16x8*)x0)[(size_t)row * 64 + lane];
    bf16x8 r;
#pragma unroll
    for (int j = 0; j < 8; ++j) {
        float x = (float)xi[j];
        r[j] = (bf16)(x + alpha * (acc[j] - x) + beta * (float)xz[j]);
    }
    ((bf16x8*)xout)[(size_t)row * 64 + lane] = r;
}

// ---------- epilogue 1 ----------
__global__ void epi1(const bf16* __restrict__ x8, const bf16* __restrict__ h,
                     const float* __restrict__ nf_p, float* __restrict__ z,
                     float* __restrict__ colsum, float* __restrict__ gst) {
    __shared__ float r1[512], r2[512];
    int b = blockIdx.x, j = threadIdx.x;
    float nf = nf_p[0];
    float cp = 0.f, sq = 0.f;
    for (int i = 0; i < 8; ++i) {
        size_t idx = (size_t)(b * 8 + i) * HIDD + j;
        float v = nf * (float)x8[idx] + (float)h[idx];
        v = fmaxf(v, 0.f);
        z[idx] = v;
        cp += v; sq += v * v;
    }
    atomicAdd(&colsum[j], cp);
    r1[j] = cp; r2[j] = sq;
    __syncthreads();
    for (int off = 256; off > 0; off >>= 1) {
        if (j < off) { r1[j] += r1[j + off]; r2[j] += r2[j + off]; }
        __syncthreads();
    }
    if (j == 0) { atomicAdd(&gst[0], r1[0]); atomicAdd(&gst[1], r2[0]); }
}

// ---------- epilogue 2 ----------
__global__ void epi2(const float* __restrict__ z, const float* __restrict__ colsum,
                     const float* __restrict__ gst, float* __restrict__ out) {
    size_t idx = (size_t)blockIdx.x * 256 + threadIdx.x;
    int j = (int)(idx & (HIDD - 1));
    float n = (float)NN * (float)HIDD;
    float gmean = gst[0] / n;
    float var = (gst[1] - n * gmean * gmean) / (n - 1.f);
    float istd = rsqrtf(var);
    float mean = colsum[j] * (1.f / (float)NN);
    out[idx] = (z[idx] - mean) * istd;
}

extern "C" void kernel_launch(void* const* d_in, const int* in_sizes, int n_in,
                              void* d_out, int out_size, void* d_ws, size_t ws_size,
                              hipStream_t stream) {
    const float* knn  = (const float*)d_in[0];
    const float* adj  = (const float*)d_in[1];
    const float* nf   = (const float*)d_in[2];
    const float* w1   = (const float*)d_in[3];
    const float* w2   = (const float*)d_in[4];
    const float* W0   = (const float*)d_in[5];
    const float* b0   = (const float*)d_in[6];
    const float* W1   = (const float*)d_in[7];
    const float* b1   = (const float*)d_in[8];
    const float* ew   = (const float*)d_in[9];
    const float* alph = (const float*)d_in[10];
    const float* beta = (const float*)d_in[11];
    const int*   ei   = (const int*)d_in[12];

    char* w = (char*)d_ws;
    size_t off = 0;
    auto alloc = [&](size_t bytes) -> char* {
        char* p = w + off;
        off += (bytes + 255) & ~(size_t)255;
        return p;
    };
    const size_t SZ_NN = (size_t)NN * NN * sizeof(bf16);       // 32 MiB
    const size_t SZ_TH = (size_t)HIDD * NN * sizeof(bf16);     // 4 MiB
    bf16*  adjT = (bf16*)alloc(SZ_NN);                // adj^T bf16
    bf16*  Par  = (bf16*)alloc(SZ_NN);                // partials / Rf fp32 / z fp32
    bf16*  knnT = (bf16*)alloc(SZ_TH);
    bf16*  tA   = (bf16*)alloc(SZ_TH);
    bf16*  tB   = (bf16*)alloc(SZ_TH);                // ends as H^T
    bf16*  Hm   = (bf16*)alloc(SZ_TH);                // H [4096,512]
    bf16*  W0b  = (bf16*)alloc(SZ_TH);
    bf16*  h1b  = (bf16*)alloc((size_t)NN * HIDD * sizeof(bf16));
    bf16*  hb   = (bf16*)alloc((size_t)NN * HIDD * sizeof(bf16));
    bf16*  xA   = (bf16*)alloc((size_t)NN * HIDD * sizeof(bf16));
    bf16*  xB   = (bf16*)alloc((size_t)NN * HIDD * sizeof(bf16));
    bf16*  Gb   = (bf16*)alloc((size_t)HIDD * HIDD * sizeof(bf16));
    bf16*  M0tb = (bf16*)alloc((size_t)HIDD * HIDD * sizeof(bf16));
    bf16*  W1b  = (bf16*)alloc((size_t)HIDD * HIDD * sizeof(bf16));
    float* inv  = (float*)alloc(NN * sizeof(float));
    float* n2   = (float*)alloc(NN * sizeof(float));
    int*   cnt  = (int*)alloc(NN * sizeof(int));
    int*   rs   = (int*)alloc((NN + 1) * sizeof(int));
    int*   cur  = (int*)alloc(NN * sizeof(int));
    int*   ccol = (int*)alloc(NE * sizeof(int));
    float* cw   = (float*)alloc(NE * sizeof(float));
    float* colsum = (float*)alloc(HIDD * sizeof(float));
    float* gst  = (float*)alloc(2 * sizeof(float));
    float* Parf = (float*)Par;
    (void)ws_size; (void)n_in; (void)in_sizes; (void)out_size;

    dim3 tb(32, 8);
    const int nTH = HIDD * NN;      // 2M elems
    const int nHH = HIDD * HIDD;    // 256K elems

    // ---- prep: knn^T (padded) and adj^T ----
    transpose_pad_f32<<<dim3(16, 128), tb, 0, stream>>>(knn, knnT, NN, 500, HIDD);
    transpose64_f32_bf16<<<dim3(64, 64), 256, 0, stream>>>(adj, adjT, NN, NN);

    // ---- chain (transposed): t1^T=knn^T w2^T ; t2^T=t1^T adj ; t3^T=t2^T w1^T ; H^T=t3^T adj^T
    // NT form, B = {w2(fp32), adjT(bf16), w1(fp32), adj(fp32)}; split-K=8 bf16 partials.
    gemm_nt<2, true ><<<dim3(32, 4, 8), 256, 0, stream>>>(knnT, w2,   Par, HIDD, NN, NN);
    reduce_bf16_slices<<<nTH / 2048, 256, 0, stream>>>(Par, tA, nTH, 8);
    gemm_nt<2, false><<<dim3(32, 4, 8), 256, 0, stream>>>(tA,   adjT, Par, HIDD, NN, NN);
    reduce_bf16_slices<<<nTH / 2048, 256, 0, stream>>>(Par, tB, nTH, 8);
    gemm_nt<2, true ><<<dim3(32, 4, 8), 256, 0, stream>>>(tB,   w1,   Par, HIDD, NN, NN);
    reduce_bf16_slices<<<nTH / 2048, 256, 0, stream>>>(Par, tA, nTH, 8);
    gemm_nt<2, true ><<<dim3(32, 4, 8), 256, 0, stream>>>(tA,   adj,  Par, HIDD, NN, NN);
    reduce_bf16_slices<<<nTH / 2048, 256, 0, stream>>>(Par, tB, nTH, 8);   // tB = H^T

    // ---- H [4096,512] ----
    transpose_bf16<<<dim3(128, 16), tb, 0, stream>>>(tB, Hm, HIDD, NN);

    // ---- G = H^T H  [512,512], split-K=16 ----
    gemm_nt<2, false><<<dim3(4, 4, 16), 256, 0, stream>>>(tB, tB, Par, HIDD, HIDD, NN);
    reduce_bf16_slices<<<nHH / 2048, 256, 0, stream>>>(Par, Gb, nHH, 16);

    // ---- R^T = G H^T  [512,4096] fp32, split-K=2 ----
    gemm_nt<0, false><<<dim3(32, 4, 2), 256, 0, stream>>>(Gb, Hm, Parf, HIDD, NN, HIDD);
    hipMemsetAsync(n2, 0, NN * sizeof(float), stream);
    colnorm_part2<<<dim3(32, 8), 128, 0, stream>>>(tB, Parf, n2);
    colnorm_fin<<<NN / 256, 256, 0, stream>>>(n2, inv);

    // ---- M0^T = W0 H  [512,512], split-K=16 ----
    cvt_f32_bf16<<<(HIDD * NN) / 1024, 256, 0, stream>>>(W0, W0b, HIDD * NN);
    gemm_nt<2, false><<<dim3(4, 4, 16), 256, 0, stream>>>(W0b, tB, Par, HIDD, HIDD, NN);
    reduce_bf16_slices<<<nHH / 2048, 256, 0, stream>>>(Par, M0tb, nHH, 16);

    // ---- h1 = diag(inv) H M0 + b0  [4096,512] bf16, split-K=2 ----
    gemm_nt<2, false><<<dim3(4, 32, 2), 256, 0, stream>>>(Hm, M0tb, Par, NN, HIDD, HIDD);
    reduce_affine512<true><<<nTH / 2048, 256, 0, stream>>>(Par, h1b, 2, inv, b0);
    // ---- h = h1 W1^T + b1  [4096,512] bf16, split-K=2 ----
    cvt_f32_bf16<<<(HIDD * HIDD) / 1024, 256, 0, stream>>>(W1, W1b, HIDD * HIDD);
    gemm_nt<2, false><<<dim3(4, 32, 2), 256, 0, stream>>>(h1b, W1b, Par, NN, HIDD, HIDD);
    reduce_affine512<false><<<nTH / 2048, 256, 0, stream>>>(Par, hb, 2, nullptr, b1);

    // ---- CSR build ----
    hipMemsetAsync(cnt, 0, NN * sizeof(int), stream);
    csr_count<<<NE / 256, 256, 0, stream>>>(ei, cnt, NE);
    scan_4096<<<1, 1024, 0, stream>>>(cnt, rs);
    hipMemcpyAsync(cur, rs, NN * sizeof(int), hipMemcpyDeviceToDevice, stream);
    csr_scatter<<<NE / 256, 256, 0, stream>>>(ei, ew, cur, ccol, cw, NE);

    // ---- 8 Euler steps (bf16 state): hb -> xA -> xB -> ... -> final in xB ----
    const bf16* xi = hb;
    bf16* xo = xA;
    for (int s = 0; s < 8; ++s) {
        ode_step_bf16<<<NN / 4, 256, 0, stream>>>(xi, hb, xo, rs, ccol, cw, alph, beta);
        xi = xo;
        xo = (s % 2 == 0) ? xB : xA;
    }

    // ---- epilogue ----
    hipMemsetAsync(colsum, 0, HIDD * sizeof(float), stream);
    hipMemsetAsync(gst, 0, 2 * sizeof(float), stream);
    epi1<<<NN / 8, 512, 0, stream>>>(xB, hb, nf, Parf, colsum, gst);
    epi2<<<(NN * HIDD) / 256, 256, 0, stream>>>(Parf, colsum, gst, (float*)d_out);
}